// Round 2
// baseline (398.045 us; speedup 1.0000x reference)
//
#include <hip/hip_runtime.h>
#include <hip/hip_bf16.h>

// Problem constants (RelKDAdapter_60284160966709)
#define D_SRC 256
#define D_REL 128

typedef short bf16x8 __attribute__((ext_vector_type(8)));
typedef float f32x4 __attribute__((ext_vector_type(4)));

__device__ __forceinline__ unsigned short f2bf(float f) {
  unsigned u = __float_as_uint(f);
  unsigned r = 0x7FFFu + ((u >> 16) & 1u);
  return (unsigned short)((u + r) >> 16);
}

__device__ __forceinline__ bf16x8 pack8(float4 a, float4 b) {
  bf16x8 o;
  o[0] = (short)f2bf(a.x); o[1] = (short)f2bf(a.y);
  o[2] = (short)f2bf(a.z); o[3] = (short)f2bf(a.w);
  o[4] = (short)f2bf(b.x); o[5] = (short)f2bf(b.y);
  o[6] = (short)f2bf(b.z); o[7] = (short)f2bf(b.w);
  return o;
}

// ---------------- W -> bf16 in MFMA B-fragment order ----------------
// Wfrag layout: [ks (8)][j (8)][lane (64)][8 bf16], 16B per (ks,j,lane) slot.
// Frag semantics (mfma_f32_16x16x32_bf16 B operand): col n = j*16 + (lane&15),
// k = ks*32 + (lane>>4)*8 + m.  Value = bf16(W[k][n]) (W stored [K=256][N=128]).
__global__ __launch_bounds__(256) void convert_wt(
    const float* __restrict__ W, unsigned short* __restrict__ Wfrag) {
  int idx = blockIdx.x * 256 + threadIdx.x;  // 0..4095 (8*8*64)
  int lane = idx & 63;
  int j = (idx >> 6) & 7;
  int ks = idx >> 9;
  int n = j * 16 + (lane & 15);
  int k = ks * 32 + (lane >> 4) * 8;
  bf16x8 o;
#pragma unroll
  for (int m = 0; m < 8; ++m)
    o[m] = (short)f2bf(W[(size_t)(k + m) * D_REL + n]);
  *(bf16x8*)(Wfrag + (size_t)idx * 8) = o;  // 16B store, frag-linear
}

// ---------------- MFMA bf16 GEMM: C = A @ W  (latency-optimized: small tiles, high occupancy) ----------------
// Each wave: 16 rows x 64 cols (acc = 4 x f32x4 = 16 VGPR).
// Block: 4 waves = 2 row-groups x 2 col-groups = 32 rows x 128 cols.
// Grid = ceil(M/32) = 3125 blocks -> thread-cap occupancy (8 blocks/CU).
// No LDS, no barriers: A-frag loads map directly onto row-major A; B frags are
// frag-linear in Wfrag (64KB, L2-resident; col-split halves per-wave B reads).
#define GBM 32

__global__ __launch_bounds__(256) void gemm_mfma(
    const float* __restrict__ A,               // [M, 256] fp32
    const unsigned short* __restrict__ Wfrag,  // [8][8][64][8] bf16 frag-order
    float* __restrict__ C,                     // [M, 128] fp32 out
    unsigned short* __restrict__ Cbf,          // [M, 128] bf16 copy (may be unused)
    int M, int write_bf) {
  const int t = threadIdx.x;
  const int w = t >> 6;        // wave 0..3
  const int lane = t & 63;
  const int quad = lane >> 4;
  const int l16 = lane & 15;
  const int row_half = w & 1;  // which 16-row group
  const int col_half = w >> 1; // which 64-col group
  const int wrow = blockIdx.x * GBM + row_half * 16;
  const int ncol0 = col_half * 64;

  f32x4 acc[4];
#pragma unroll
  for (int j = 0; j < 4; ++j) acc[j] = (f32x4)(0.0f);

  const int r0 = wrow + l16;
  const bool v0 = r0 < M;
  const float* a0 = A + (size_t)r0 * D_SRC + quad * 8;
  // B slot index: (ks*8 + col_half*4 + j)*64 + lane
  const bf16x8* bbase = (const bf16x8*)Wfrag + (size_t)col_half * 4 * 64 + lane;

  const float4 z4 = make_float4(0.f, 0.f, 0.f, 0.f);

#pragma unroll
  for (int ks = 0; ks < 8; ++ks) {
    // A frag: per lane 32B contiguous from its row, k = ks*32 + quad*8
    float4 x0 = v0 ? *(const float4*)(a0 + ks * 32) : z4;
    float4 x1 = v0 ? *(const float4*)(a0 + ks * 32 + 4) : z4;

    // B frags: 4 coalesced 16B loads (same addrs across co-resident waves -> L2 hits)
    bf16x8 bfr[4];
#pragma unroll
    for (int j = 0; j < 4; ++j) bfr[j] = bbase[((size_t)ks * 8 + j) * 64];

    bf16x8 af = pack8(x0, x1);

#pragma unroll
    for (int j = 0; j < 4; ++j)
      acc[j] = __builtin_amdgcn_mfma_f32_16x16x32_bf16(af, bfr[j], acc[j], 0, 0, 0);
  }

  // Epilogue: C/D layout col=lane&15, row=quad*4+reg
#pragma unroll
  for (int r = 0; r < 4; ++r) {
    int grow = wrow + quad * 4 + r;
    if (grow < M) {
#pragma unroll
      for (int j = 0; j < 4; ++j) {
        int gcol = ncol0 + j * 16 + l16;
        float val = acc[j][r];
        C[(size_t)grow * D_REL + gcol] = val;
        if (write_bf) Cbf[(size_t)grow * D_REL + gcol] = f2bf(val);
      }
    }
  }
}

// ---------------- Degree count ----------------
__global__ __launch_bounds__(256) void deg_count(
    const int* __restrict__ edge_row, int E, int* __restrict__ cnt) {
  int i = blockIdx.x * blockDim.x + threadIdx.x;
  if (i < E) atomicAdd(&cnt[edge_row[i]], 1);
}

__global__ __launch_bounds__(256) void deg_finalize(
    const int* __restrict__ cnt, int n,
    float* __restrict__ deg_out, float* __restrict__ inv_deg) {
  int i = blockIdx.x * blockDim.x + threadIdx.x;
  if (i < n) {
    int c = cnt[i];
    float d = (float)(c > 1 ? c : 1);
    deg_out[i] = d;
    inv_deg[i] = 1.0f / d;
  }
}

// ---------------- Exclusive scan of cnt -> row_ptr ----------------
#define SCAN_B 256

__global__ __launch_bounds__(SCAN_B) void scan1(
    const int* __restrict__ cnt, int n,
    int* __restrict__ row_ptr, int* __restrict__ block_sums) {
  __shared__ int s[SCAN_B];
  int i = blockIdx.x * SCAN_B + threadIdx.x;
  int v = (i < n) ? cnt[i] : 0;
  s[threadIdx.x] = v;
  __syncthreads();
#pragma unroll
  for (int off = 1; off < SCAN_B; off <<= 1) {
    int add = (threadIdx.x >= off) ? s[threadIdx.x - off] : 0;
    __syncthreads();
    s[threadIdx.x] += add;
    __syncthreads();
  }
  if (i < n) row_ptr[i] = s[threadIdx.x] - v;
  if (threadIdx.x == SCAN_B - 1) block_sums[blockIdx.x] = s[SCAN_B - 1];
}

__global__ __launch_bounds__(512) void scan2(
    int* __restrict__ block_sums, int nblocks) {
  __shared__ int s[512];
  int v = (threadIdx.x < nblocks) ? block_sums[threadIdx.x] : 0;
  s[threadIdx.x] = v;
  __syncthreads();
#pragma unroll
  for (int off = 1; off < 512; off <<= 1) {
    int add = (threadIdx.x >= off) ? s[threadIdx.x - off] : 0;
    __syncthreads();
    s[threadIdx.x] += add;
    __syncthreads();
  }
  if (threadIdx.x < nblocks) block_sums[threadIdx.x] = s[threadIdx.x] - v;
}

__global__ __launch_bounds__(SCAN_B) void scan3(
    int* __restrict__ row_ptr, const int* __restrict__ block_sums,
    int* __restrict__ cursor, int n, int E) {
  int i = blockIdx.x * SCAN_B + threadIdx.x;
  if (i < n) {
    int v = row_ptr[i] + block_sums[blockIdx.x];
    row_ptr[i] = v;
    cursor[i] = v;
  }
  if (i == 0) row_ptr[n] = E;
}

// ---------------- Scatter edges into CSR order ----------------
__global__ __launch_bounds__(256) void scatter_edges(
    const int* __restrict__ edge_row, const int* __restrict__ edge_col,
    int* __restrict__ cursor, int* __restrict__ sorted_col, int E) {
  int e = blockIdx.x * blockDim.x + threadIdx.x;
  if (e < E) {
    int r = edge_row[e];
    int pos = atomicAdd(&cursor[r], 1);
    sorted_col[pos] = edge_col[e];
  }
}

// ---------------- CSR aggregate (bf16 gather): one wave per dst row ----------------
__global__ __launch_bounds__(256) void aggregate_csr_bf16(
    const int* __restrict__ row_ptr, const int* __restrict__ sorted_col,
    const unsigned short* __restrict__ srcb, const float* __restrict__ inv_deg,
    float* __restrict__ dst, int n) {
  int wave = (blockIdx.x * blockDim.x + threadIdx.x) >> 6;
  int lane = threadIdx.x & 63;
  if (wave >= n) return;
  int beg = row_ptr[wave];
  int end = row_ptr[wave + 1];
  const unsigned short* base = srcb + lane * 2;
  float ax = 0.f, ay = 0.f, bx = 0.f, by = 0.f;
  int e = beg;
  for (; e + 1 < end; e += 2) {
    unsigned u0 = *(const unsigned*)(base + (size_t)sorted_col[e] * D_REL);
    unsigned u1 = *(const unsigned*)(base + (size_t)sorted_col[e + 1] * D_REL);
    ax += __uint_as_float(u0 << 16);
    ay += __uint_as_float(u0 & 0xffff0000u);
    bx += __uint_as_float(u1 << 16);
    by += __uint_as_float(u1 & 0xffff0000u);
  }
  if (e < end) {
    unsigned u0 = *(const unsigned*)(base + (size_t)sorted_col[e] * D_REL);
    ax += __uint_as_float(u0 << 16);
    ay += __uint_as_float(u0 & 0xffff0000u);
  }
  float wgt = inv_deg[wave];
  float2 o;
  o.x = (ax + bx) * wgt;
  o.y = (ay + by) * wgt;
  *(float2*)(dst + (size_t)wave * D_REL + lane * 2) = o;
}

// ---------------- CSR aggregate (fp32 gather fallback) ----------------
__global__ __launch_bounds__(256) void aggregate_csr(
    const int* __restrict__ row_ptr, const int* __restrict__ sorted_col,
    const float* __restrict__ src_proj, const float* __restrict__ inv_deg,
    float* __restrict__ dst, int n) {
  int wave = (blockIdx.x * blockDim.x + threadIdx.x) >> 6;
  int lane = threadIdx.x & 63;
  if (wave >= n) return;
  int beg = row_ptr[wave];
  int end = row_ptr[wave + 1];
  const float* base = src_proj + lane * 2;
  float ax = 0.f, ay = 0.f, bx = 0.f, by = 0.f;
  int e = beg;
  for (; e + 1 < end; e += 2) {
    int c0 = sorted_col[e];
    int c1 = sorted_col[e + 1];
    float2 v0 = *(const float2*)(base + (size_t)c0 * D_REL);
    float2 v1 = *(const float2*)(base + (size_t)c1 * D_REL);
    ax += v0.x; ay += v0.y;
    bx += v1.x; by += v1.y;
  }
  if (e < end) {
    int c0 = sorted_col[e];
    float2 v0 = *(const float2*)(base + (size_t)c0 * D_REL);
    ax += v0.x; ay += v0.y;
  }
  float w = inv_deg[wave];
  float2 o;
  o.x = (ax + bx) * w;
  o.y = (ay + by) * w;
  *(float2*)(dst + (size_t)wave * D_REL + lane * 2) = o;
}

extern "C" void kernel_launch(void* const* d_in, const int* in_sizes, int n_in,
                              void* d_out, int out_size, void* d_ws, size_t ws_size,
                              hipStream_t stream) {
  const float* x_src = (const float*)d_in[0];
  // d_in[1] = x_dst, d_in[3] = W_dst: dead (dst_proj is deleted in reference)
  const float* W_src = (const float*)d_in[2];
  const int* edge_row = (const int*)d_in[4];
  const int* edge_col = (const int*)d_in[5];

  const int M = in_sizes[0] / D_SRC;   // N_SRC = 100000
  const int N = in_sizes[1] / 64;      // N_DST = 100000
  const int E = in_sizes[4];           // 640000

  float* out = (float*)d_out;
  float* out_dst = out;                                  // [N, 128]
  float* out_src_proj = out + (size_t)N * D_REL;         // [M, 128]
  float* out_deg = out_src_proj + (size_t)M * D_REL;     // [N]

  // Workspace layout (256B-aligned slabs)
  char* ws = (char*)d_ws;
  size_t off = 0;
  auto alloc = [&](size_t bytes) {
    char* p = ws + off;
    off = (off + bytes + 255) & ~(size_t)255;
    return p;
  };
  int* cnt        = (int*)alloc((size_t)N * sizeof(int));
  int* row_ptr    = (int*)alloc((size_t)(N + 1) * sizeof(int));
  int* cursor     = (int*)alloc((size_t)N * sizeof(int));
  int* sorted_col = (int*)alloc((size_t)E * sizeof(int));
  float* inv_deg  = (float*)alloc((size_t)N * sizeof(float));
  int* block_sums = (int*)alloc(512 * sizeof(int));
  unsigned short* WT = (unsigned short*)alloc((size_t)D_REL * D_SRC * sizeof(unsigned short));
  size_t base_need = off;
  unsigned short* src_bf = (unsigned short*)alloc((size_t)M * D_REL * sizeof(unsigned short));
  const bool use_bf = (ws_size >= off);
  (void)base_need;

  const int scan_blocks = (N + SCAN_B - 1) / SCAN_B;  // 391 <= 512

  hipMemsetAsync(cnt, 0, (size_t)N * sizeof(int), stream);

  // W bf16, MFMA B-fragment order: 8*8*64 slots of 8 bf16 = 4096 threads
  convert_wt<<<16, 256, 0, stream>>>(W_src, WT);

  // Degree + inv_deg
  deg_count<<<(E + 255) / 256, 256, 0, stream>>>(edge_row, E, cnt);
  deg_finalize<<<(N + 255) / 256, 256, 0, stream>>>(cnt, N, out_deg, inv_deg);

  // Exclusive scan cnt -> row_ptr; cursor = row_ptr
  scan1<<<scan_blocks, SCAN_B, 0, stream>>>(cnt, N, row_ptr, block_sums);
  scan2<<<1, 512, 0, stream>>>(block_sums, scan_blocks);
  scan3<<<scan_blocks, SCAN_B, 0, stream>>>(row_ptr, block_sums, cursor, N, E);

  // CSR scatter
  scatter_edges<<<(E + 255) / 256, 256, 0, stream>>>(edge_row, edge_col, cursor,
                                                     sorted_col, E);

  // MFMA GEMM: src_proj fp32 (+ bf16 copy for the gather if ws allows)
  gemm_mfma<<<(M + GBM - 1) / GBM, 256, 0, stream>>>(
      x_src, WT, out_src_proj, src_bf, M, use_bf ? 1 : 0);

  // Gather-aggregate: 1 wave per dst row, 4 waves per block
  if (use_bf) {
    aggregate_csr_bf16<<<(N + 3) / 4, 256, 0, stream>>>(row_ptr, sorted_col, src_bf,
                                                        inv_deg, out_dst, N);
  } else {
    aggregate_csr<<<(N + 3) / 4, 256, 0, stream>>>(row_ptr, sorted_col, out_src_proj,
                                                   inv_deg, out_dst, N);
  }
}

// Round 3
// 375.674 us; speedup vs baseline: 1.0596x; 1.0596x over previous
//
#include <hip/hip_runtime.h>
#include <hip/hip_bf16.h>

// Problem constants (RelKDAdapter_60284160966709)
#define D_SRC 256
#define D_REL 128

typedef short bf16x8 __attribute__((ext_vector_type(8)));
typedef float f32x4 __attribute__((ext_vector_type(4)));

__device__ __forceinline__ unsigned short f2bf(float f) {
  unsigned u = __float_as_uint(f);
  unsigned r = 0x7FFFu + ((u >> 16) & 1u);
  return (unsigned short)((u + r) >> 16);
}

// 2x fp32 -> packed bf16 pair via v_cvt_pk_bf16_f32 (compiler-generated, RNE)
__device__ __forceinline__ unsigned cvt2(float lo, float hi) {
  __hip_bfloat162 h = __float22bfloat162_rn(make_float2(lo, hi));
  return *reinterpret_cast<unsigned*>(&h);
}

__device__ __forceinline__ bf16x8 pack8(float4 a, float4 b) {
  union { unsigned u[4]; bf16x8 v; } r;
  r.u[0] = cvt2(a.x, a.y);
  r.u[1] = cvt2(a.z, a.w);
  r.u[2] = cvt2(b.x, b.y);
  r.u[3] = cvt2(b.z, b.w);
  return r.v;
}

// ---------------- W -> bf16 in MFMA B-fragment order ----------------
// Wfrag layout: [ks (8)][j (8)][lane (64)][8 bf16], 16B per (ks,j,lane) slot.
// Frag semantics (mfma_f32_16x16x32_bf16 B operand): col n = j*16 + (lane&15),
// k = ks*32 + (lane>>4)*8 + m.  Value = bf16(W[k][n]) (W stored [K=256][N=128]).
// Layout harness-verified in rounds 1-2 (passed, absmax 0.03125).
__global__ __launch_bounds__(256) void convert_wt(
    const float* __restrict__ W, unsigned short* __restrict__ Wfrag) {
  int idx = blockIdx.x * 256 + threadIdx.x;  // 0..4095 (8*8*64)
  int lane = idx & 63;
  int j = (idx >> 6) & 7;
  int ks = idx >> 9;
  int n = j * 16 + (lane & 15);
  int k = ks * 32 + (lane >> 4) * 8;
  bf16x8 o;
#pragma unroll
  for (int m = 0; m < 8; ++m)
    o[m] = (short)f2bf(W[(size_t)(k + m) * D_REL + n]);
  *(bf16x8*)(Wfrag + (size_t)idx * 8) = o;  // 16B store, frag-linear
}

// ---------------- MFMA bf16 GEMM: C = A @ W ----------------
// Structure (round-3): B staged into LDS ONCE (64 KB frag-linear; contiguous
// ds_read_b128, no bank pathology), A loaded per-lane direct from global
// (A-frag layout == row-major A), fp32->bf16 via v_cvt_pk. ZERO barriers in
// the k-loop -> compiler pipelines all 8 unrolled ksteps with counted
// vmcnt/lgkmcnt. Wave = 32 rows x 128 cols (acc 2x8 f32x4 = 64 VGPR, deep ILP).
// 4 waves/block = 128 rows; grid = ceil(M/128) = 782.
#define GBM 128

__global__ __launch_bounds__(256) void gemm_mfma(
    const float* __restrict__ A,               // [M, 256] fp32
    const unsigned short* __restrict__ Wfrag,  // [8][8][64][8] bf16 frag-order
    float* __restrict__ C,                     // [M, 128] fp32 out
    unsigned short* __restrict__ Cbf,          // [M, 128] bf16 copy (may be unused)
    int M, int write_bf) {
  __shared__ unsigned short Bs[8 * 8 * 64 * 8];  // 64 KB, frag-linear

  const int t = threadIdx.x;

  // Stage all of B once: 4096 x 16B slots, 16 per thread, coalesced.
#pragma unroll
  for (int i = 0; i < 16; ++i) {
    int s = t + 256 * i;
    *(uint4*)(Bs + (size_t)s * 8) = *(const uint4*)(Wfrag + (size_t)s * 8);
  }
  __syncthreads();  // only barrier in the kernel

  const int w = t >> 6;        // wave 0..3
  const int lane = t & 63;
  const int quad = lane >> 4;
  const int l16 = lane & 15;
  const int wrow = blockIdx.x * GBM + w * 32;  // wave's 32-row slice

  f32x4 acc[2][8];
#pragma unroll
  for (int i = 0; i < 2; ++i)
#pragma unroll
    for (int j = 0; j < 8; ++j) acc[i][j] = (f32x4)(0.0f);

  const int r0 = wrow + l16;        // row tile i=0
  const int r1 = r0 + 16;           // row tile i=1
  const bool v0 = r0 < M;
  const bool v1 = r1 < M;
  const float* a0 = A + (size_t)r0 * D_SRC + quad * 8;
  const float* a1 = A + (size_t)r1 * D_SRC + quad * 8;
  const float4 z4 = make_float4(0.f, 0.f, 0.f, 0.f);

#pragma unroll
  for (int ks = 0; ks < 8; ++ks) {
    // A frags: per lane 32B contiguous from its own row, k = ks*32 + quad*8
    float4 x0 = v0 ? *(const float4*)(a0 + ks * 32) : z4;
    float4 x1 = v0 ? *(const float4*)(a0 + ks * 32 + 4) : z4;
    float4 y0 = v1 ? *(const float4*)(a1 + ks * 32) : z4;
    float4 y1 = v1 ? *(const float4*)(a1 + ks * 32 + 4) : z4;

    bf16x8 af0 = pack8(x0, x1);
    bf16x8 af1 = pack8(y0, y1);

#pragma unroll
    for (int j = 0; j < 8; ++j) {
      bf16x8 bfr = *(const bf16x8*)(Bs + (((size_t)ks * 8 + j) * 64 + lane) * 8);
      acc[0][j] = __builtin_amdgcn_mfma_f32_16x16x32_bf16(af0, bfr, acc[0][j], 0, 0, 0);
      acc[1][j] = __builtin_amdgcn_mfma_f32_16x16x32_bf16(af1, bfr, acc[1][j], 0, 0, 0);
    }
  }

  // Epilogue: C/D layout col=lane&15, row=quad*4+reg
#pragma unroll
  for (int i = 0; i < 2; ++i) {
#pragma unroll
    for (int r = 0; r < 4; ++r) {
      int grow = wrow + i * 16 + quad * 4 + r;
      if (grow < M) {
#pragma unroll
        for (int j = 0; j < 8; ++j) {
          int gcol = j * 16 + l16;
          float val = acc[i][j][r];
          C[(size_t)grow * D_REL + gcol] = val;
          if (write_bf) Cbf[(size_t)grow * D_REL + gcol] = f2bf(val);
        }
      }
    }
  }
}

// ---------------- Degree count ----------------
__global__ __launch_bounds__(256) void deg_count(
    const int* __restrict__ edge_row, int E, int* __restrict__ cnt) {
  int i = blockIdx.x * blockDim.x + threadIdx.x;
  if (i < E) atomicAdd(&cnt[edge_row[i]], 1);
}

__global__ __launch_bounds__(256) void deg_finalize(
    const int* __restrict__ cnt, int n,
    float* __restrict__ deg_out, float* __restrict__ inv_deg) {
  int i = blockIdx.x * blockDim.x + threadIdx.x;
  if (i < n) {
    int c = cnt[i];
    float d = (float)(c > 1 ? c : 1);
    deg_out[i] = d;
    inv_deg[i] = 1.0f / d;
  }
}

// ---------------- Exclusive scan of cnt -> row_ptr ----------------
#define SCAN_B 256

__global__ __launch_bounds__(SCAN_B) void scan1(
    const int* __restrict__ cnt, int n,
    int* __restrict__ row_ptr, int* __restrict__ block_sums) {
  __shared__ int s[SCAN_B];
  int i = blockIdx.x * SCAN_B + threadIdx.x;
  int v = (i < n) ? cnt[i] : 0;
  s[threadIdx.x] = v;
  __syncthreads();
#pragma unroll
  for (int off = 1; off < SCAN_B; off <<= 1) {
    int add = (threadIdx.x >= off) ? s[threadIdx.x - off] : 0;
    __syncthreads();
    s[threadIdx.x] += add;
    __syncthreads();
  }
  if (i < n) row_ptr[i] = s[threadIdx.x] - v;
  if (threadIdx.x == SCAN_B - 1) block_sums[blockIdx.x] = s[SCAN_B - 1];
}

__global__ __launch_bounds__(512) void scan2(
    int* __restrict__ block_sums, int nblocks) {
  __shared__ int s[512];
  int v = (threadIdx.x < nblocks) ? block_sums[threadIdx.x] : 0;
  s[threadIdx.x] = v;
  __syncthreads();
#pragma unroll
  for (int off = 1; off < 512; off <<= 1) {
    int add = (threadIdx.x >= off) ? s[threadIdx.x - off] : 0;
    __syncthreads();
    s[threadIdx.x] += add;
    __syncthreads();
  }
  if (threadIdx.x < nblocks) block_sums[threadIdx.x] = s[threadIdx.x] - v;
}

__global__ __launch_bounds__(SCAN_B) void scan3(
    int* __restrict__ row_ptr, const int* __restrict__ block_sums,
    int* __restrict__ cursor, int n, int E) {
  int i = blockIdx.x * SCAN_B + threadIdx.x;
  if (i < n) {
    int v = row_ptr[i] + block_sums[blockIdx.x];
    row_ptr[i] = v;
    cursor[i] = v;
  }
  if (i == 0) row_ptr[n] = E;
}

// ---------------- Scatter edges into CSR order ----------------
__global__ __launch_bounds__(256) void scatter_edges(
    const int* __restrict__ edge_row, const int* __restrict__ edge_col,
    int* __restrict__ cursor, int* __restrict__ sorted_col, int E) {
  int e = blockIdx.x * blockDim.x + threadIdx.x;
  if (e < E) {
    int r = edge_row[e];
    int pos = atomicAdd(&cursor[r], 1);
    sorted_col[pos] = edge_col[e];
  }
}

// ---------------- CSR aggregate (bf16 gather): one wave per dst row ----------------
__global__ __launch_bounds__(256) void aggregate_csr_bf16(
    const int* __restrict__ row_ptr, const int* __restrict__ sorted_col,
    const unsigned short* __restrict__ srcb, const float* __restrict__ inv_deg,
    float* __restrict__ dst, int n) {
  int wave = (blockIdx.x * blockDim.x + threadIdx.x) >> 6;
  int lane = threadIdx.x & 63;
  if (wave >= n) return;
  int beg = row_ptr[wave];
  int end = row_ptr[wave + 1];
  const unsigned short* base = srcb + lane * 2;
  float ax = 0.f, ay = 0.f, bx = 0.f, by = 0.f;
  int e = beg;
  for (; e + 1 < end; e += 2) {
    unsigned u0 = *(const unsigned*)(base + (size_t)sorted_col[e] * D_REL);
    unsigned u1 = *(const unsigned*)(base + (size_t)sorted_col[e + 1] * D_REL);
    ax += __uint_as_float(u0 << 16);
    ay += __uint_as_float(u0 & 0xffff0000u);
    bx += __uint_as_float(u1 << 16);
    by += __uint_as_float(u1 & 0xffff0000u);
  }
  if (e < end) {
    unsigned u0 = *(const unsigned*)(base + (size_t)sorted_col[e] * D_REL);
    ax += __uint_as_float(u0 << 16);
    ay += __uint_as_float(u0 & 0xffff0000u);
  }
  float wgt = inv_deg[wave];
  float2 o;
  o.x = (ax + bx) * wgt;
  o.y = (ay + by) * wgt;
  *(float2*)(dst + (size_t)wave * D_REL + lane * 2) = o;
}

// ---------------- CSR aggregate (fp32 gather fallback) ----------------
__global__ __launch_bounds__(256) void aggregate_csr(
    const int* __restrict__ row_ptr, const int* __restrict__ sorted_col,
    const float* __restrict__ src_proj, const float* __restrict__ inv_deg,
    float* __restrict__ dst, int n) {
  int wave = (blockIdx.x * blockDim.x + threadIdx.x) >> 6;
  int lane = threadIdx.x & 63;
  if (wave >= n) return;
  int beg = row_ptr[wave];
  int end = row_ptr[wave + 1];
  const float* base = src_proj + lane * 2;
  float ax = 0.f, ay = 0.f, bx = 0.f, by = 0.f;
  int e = beg;
  for (; e + 1 < end; e += 2) {
    int c0 = sorted_col[e];
    int c1 = sorted_col[e + 1];
    float2 v0 = *(const float2*)(base + (size_t)c0 * D_REL);
    float2 v1 = *(const float2*)(base + (size_t)c1 * D_REL);
    ax += v0.x; ay += v0.y;
    bx += v1.x; by += v1.y;
  }
  if (e < end) {
    int c0 = sorted_col[e];
    float2 v0 = *(const float2*)(base + (size_t)c0 * D_REL);
    ax += v0.x; ay += v0.y;
  }
  float w = inv_deg[wave];
  float2 o;
  o.x = (ax + bx) * w;
  o.y = (ay + by) * w;
  *(float2*)(dst + (size_t)wave * D_REL + lane * 2) = o;
}

extern "C" void kernel_launch(void* const* d_in, const int* in_sizes, int n_in,
                              void* d_out, int out_size, void* d_ws, size_t ws_size,
                              hipStream_t stream) {
  const float* x_src = (const float*)d_in[0];
  // d_in[1] = x_dst, d_in[3] = W_dst: dead (dst_proj is deleted in reference)
  const float* W_src = (const float*)d_in[2];
  const int* edge_row = (const int*)d_in[4];
  const int* edge_col = (const int*)d_in[5];

  const int M = in_sizes[0] / D_SRC;   // N_SRC = 100000
  const int N = in_sizes[1] / 64;      // N_DST = 100000
  const int E = in_sizes[4];           // 640000

  float* out = (float*)d_out;
  float* out_dst = out;                                  // [N, 128]
  float* out_src_proj = out + (size_t)N * D_REL;         // [M, 128]
  float* out_deg = out_src_proj + (size_t)M * D_REL;     // [N]

  // Workspace layout (256B-aligned slabs)
  char* ws = (char*)d_ws;
  size_t off = 0;
  auto alloc = [&](size_t bytes) {
    char* p = ws + off;
    off = (off + bytes + 255) & ~(size_t)255;
    return p;
  };
  int* cnt        = (int*)alloc((size_t)N * sizeof(int));
  int* row_ptr    = (int*)alloc((size_t)(N + 1) * sizeof(int));
  int* cursor     = (int*)alloc((size_t)N * sizeof(int));
  int* sorted_col = (int*)alloc((size_t)E * sizeof(int));
  float* inv_deg  = (float*)alloc((size_t)N * sizeof(float));
  int* block_sums = (int*)alloc(512 * sizeof(int));
  unsigned short* WT = (unsigned short*)alloc((size_t)D_REL * D_SRC * sizeof(unsigned short));
  size_t base_need = off;
  unsigned short* src_bf = (unsigned short*)alloc((size_t)M * D_REL * sizeof(unsigned short));
  const bool use_bf = (ws_size >= off);
  (void)base_need;

  const int scan_blocks = (N + SCAN_B - 1) / SCAN_B;  // 391 <= 512

  hipMemsetAsync(cnt, 0, (size_t)N * sizeof(int), stream);

  // W bf16, MFMA B-fragment order: 8*8*64 slots of 8 bf16 = 4096 threads
  convert_wt<<<16, 256, 0, stream>>>(W_src, WT);

  // Degree + inv_deg
  deg_count<<<(E + 255) / 256, 256, 0, stream>>>(edge_row, E, cnt);
  deg_finalize<<<(N + 255) / 256, 256, 0, stream>>>(cnt, N, out_deg, inv_deg);

  // Exclusive scan cnt -> row_ptr; cursor = row_ptr
  scan1<<<scan_blocks, SCAN_B, 0, stream>>>(cnt, N, row_ptr, block_sums);
  scan2<<<1, 512, 0, stream>>>(block_sums, scan_blocks);
  scan3<<<scan_blocks, SCAN_B, 0, stream>>>(row_ptr, block_sums, cursor, N, E);

  // CSR scatter
  scatter_edges<<<(E + 255) / 256, 256, 0, stream>>>(edge_row, edge_col, cursor,
                                                     sorted_col, E);

  // MFMA GEMM: src_proj fp32 (+ bf16 copy for the gather if ws allows)
  gemm_mfma<<<(M + GBM - 1) / GBM, 256, 0, stream>>>(
      x_src, WT, out_src_proj, src_bf, M, use_bf ? 1 : 0);

  // Gather-aggregate: 1 wave per dst row, 4 waves per block
  if (use_bf) {
    aggregate_csr_bf16<<<(N + 3) / 4, 256, 0, stream>>>(row_ptr, sorted_col, src_bf,
                                                        inv_deg, out_dst, N);
  } else {
    aggregate_csr<<<(N + 3) / 4, 256, 0, stream>>>(row_ptr, sorted_col, out_src_proj,
                                                   inv_deg, out_dst, N);
  }
}

// Round 4
// 337.971 us; speedup vs baseline: 1.1777x; 1.1116x over previous
//
#include <hip/hip_runtime.h>
#include <hip/hip_bf16.h>

// Problem constants (RelKDAdapter_60284160966709)
#define D_SRC 256
#define D_REL 128

typedef short bf16x8 __attribute__((ext_vector_type(8)));
typedef float f32x4 __attribute__((ext_vector_type(4)));

__device__ __forceinline__ unsigned short f2bf(float f) {
  unsigned u = __float_as_uint(f);
  unsigned r = 0x7FFFu + ((u >> 16) & 1u);
  return (unsigned short)((u + r) >> 16);
}

// 2x fp32 -> packed bf16 pair via v_cvt_pk_bf16_f32 (compiler-generated, RNE)
__device__ __forceinline__ unsigned cvt2(float lo, float hi) {
  __hip_bfloat162 h = __float22bfloat162_rn(make_float2(lo, hi));
  return *reinterpret_cast<unsigned*>(&h);
}

__device__ __forceinline__ bf16x8 pack8(float4 a, float4 b) {
  union { unsigned u[4]; bf16x8 v; } r;
  r.u[0] = cvt2(a.x, a.y);
  r.u[1] = cvt2(a.z, a.w);
  r.u[2] = cvt2(b.x, b.y);
  r.u[3] = cvt2(b.z, b.w);
  return r.v;
}

// ---------------- A fp32 -> bf16 row-major (streaming, BW-bound) ----------------
// One thread per 8 elements: 2x float4 load (32B), 4x v_cvt_pk, 1x 16B store.
__global__ __launch_bounds__(256) void convert_a(
    const float* __restrict__ A, unsigned short* __restrict__ Abf, long total8) {
  long i = (long)blockIdx.x * 256 + threadIdx.x;
  if (i >= total8) return;
  const float4* p = (const float4*)(A + i * 8);
  float4 a = p[0];
  float4 b = p[1];
  union { unsigned u[4]; uint4 v; } r;
  r.u[0] = cvt2(a.x, a.y);
  r.u[1] = cvt2(a.z, a.w);
  r.u[2] = cvt2(b.x, b.y);
  r.u[3] = cvt2(b.z, b.w);
  *(uint4*)(Abf + i * 8) = r.v;
}

// ---------------- W -> bf16 in MFMA B-fragment order ----------------
// Wfrag layout: [ks (8)][j (8)][lane (64)][8 bf16], 16B per (ks,j,lane) slot.
// Frag semantics (mfma_f32_16x16x32_bf16 B operand): col n = j*16 + (lane&15),
// k = ks*32 + (lane>>4)*8 + m.  Value = bf16(W[k][n]) (W stored [K=256][N=128]).
// Layout harness-verified rounds 1-3 (passed, absmax 0.03125).
__global__ __launch_bounds__(256) void convert_wt(
    const float* __restrict__ W, unsigned short* __restrict__ Wfrag) {
  int idx = blockIdx.x * 256 + threadIdx.x;  // 0..4095 (8*8*64)
  int lane = idx & 63;
  int j = (idx >> 6) & 7;
  int ks = idx >> 9;
  int n = j * 16 + (lane & 15);
  int k = ks * 32 + (lane >> 4) * 8;
  bf16x8 o;
#pragma unroll
  for (int m = 0; m < 8; ++m)
    o[m] = (short)f2bf(W[(size_t)(k + m) * D_REL + n]);
  *(bf16x8*)(Wfrag + (size_t)idx * 8) = o;  // 16B store, frag-linear
}

#define GBM 128

// ---------------- MFMA GEMM v4: bf16 A, register-resident A-frags ----------------
// Per wave (32 rows x 128 cols): issue ALL 16 A-frag loads up front (one 16B
// load per frag -- row-major bf16 A IS the A-frag layout), stage B to LDS once,
// one barrier, then pure ds_read_b128 + 128 MFMA stream. No loads on the
// k-loop critical path. Rows clamped to M-1 so loads are unconditional.
__global__ __launch_bounds__(256, 2) void gemm_mfma_bf(
    const unsigned short* __restrict__ Abf,    // [M, 256] bf16
    const unsigned short* __restrict__ Wfrag,  // [8][8][64][8] bf16 frag-order
    float* __restrict__ C,                     // [M, 128] fp32 out
    unsigned short* __restrict__ Cbf,          // [M, 128] bf16 copy
    int M, int write_bf) {
  __shared__ unsigned short Bs[8 * 8 * 64 * 8];  // 64 KB, frag-linear

  const int t = threadIdx.x;
  const int w = t >> 6;
  const int lane = t & 63;
  const int quad = lane >> 4;
  const int l16 = lane & 15;
  const int wrow = blockIdx.x * GBM + w * 32;

  const int r0 = wrow + l16;
  const int r1 = r0 + 16;
  const int r0c = (r0 < M) ? r0 : (M - 1);   // clamp: branchless, always-valid loads
  const int r1c = (r1 < M) ? r1 : (M - 1);
  const unsigned short* a0 = Abf + (size_t)r0c * D_SRC + quad * 8;
  const unsigned short* a1 = Abf + (size_t)r1c * D_SRC + quad * 8;

  // --- Issue all 16 A-frag loads back-to-back (64 VGPR in flight) ---
  bf16x8 afr0[8], afr1[8];
#pragma unroll
  for (int ks = 0; ks < 8; ++ks) afr0[ks] = *(const bf16x8*)(a0 + ks * 32);
#pragma unroll
  for (int ks = 0; ks < 8; ++ks) afr1[ks] = *(const bf16x8*)(a1 + ks * 32);

  // --- Stage all of B once: 4096 x 16B slots, 16 per thread, coalesced ---
#pragma unroll
  for (int i = 0; i < 16; ++i) {
    int s = t + 256 * i;
    *(uint4*)(Bs + (size_t)s * 8) = *(const uint4*)(Wfrag + (size_t)s * 8);
  }
  __syncthreads();  // only barrier in the kernel

  f32x4 acc[2][8];
#pragma unroll
  for (int i = 0; i < 2; ++i)
#pragma unroll
    for (int j = 0; j < 8; ++j) acc[i][j] = (f32x4)(0.0f);

  // --- Pure LDS-read + MFMA stream ---
#pragma unroll
  for (int ks = 0; ks < 8; ++ks) {
#pragma unroll
    for (int j = 0; j < 8; ++j) {
      bf16x8 bfr = *(const bf16x8*)(Bs + (((size_t)ks * 8 + j) * 64 + lane) * 8);
      acc[0][j] = __builtin_amdgcn_mfma_f32_16x16x32_bf16(afr0[ks], bfr, acc[0][j], 0, 0, 0);
      acc[1][j] = __builtin_amdgcn_mfma_f32_16x16x32_bf16(afr1[ks], bfr, acc[1][j], 0, 0, 0);
    }
  }

  // Epilogue: C/D layout col=lane&15, row=quad*4+reg
#pragma unroll
  for (int i = 0; i < 2; ++i) {
#pragma unroll
    for (int r = 0; r < 4; ++r) {
      int grow = wrow + i * 16 + quad * 4 + r;
      if (grow < M) {
#pragma unroll
        for (int j = 0; j < 8; ++j) {
          int gcol = j * 16 + l16;
          float val = acc[i][j][r];
          C[(size_t)grow * D_REL + gcol] = val;
          if (write_bf) Cbf[(size_t)grow * D_REL + gcol] = f2bf(val);
        }
      }
    }
  }
}

// ---------------- MFMA GEMM (fp32-A fallback, r3 structure) ----------------
__global__ __launch_bounds__(256) void gemm_mfma(
    const float* __restrict__ A,               // [M, 256] fp32
    const unsigned short* __restrict__ Wfrag,  // [8][8][64][8] bf16 frag-order
    float* __restrict__ C,
    unsigned short* __restrict__ Cbf,
    int M, int write_bf) {
  __shared__ unsigned short Bs[8 * 8 * 64 * 8];  // 64 KB

  const int t = threadIdx.x;
#pragma unroll
  for (int i = 0; i < 16; ++i) {
    int s = t + 256 * i;
    *(uint4*)(Bs + (size_t)s * 8) = *(const uint4*)(Wfrag + (size_t)s * 8);
  }
  __syncthreads();

  const int w = t >> 6;
  const int lane = t & 63;
  const int quad = lane >> 4;
  const int l16 = lane & 15;
  const int wrow = blockIdx.x * GBM + w * 32;

  f32x4 acc[2][8];
#pragma unroll
  for (int i = 0; i < 2; ++i)
#pragma unroll
    for (int j = 0; j < 8; ++j) acc[i][j] = (f32x4)(0.0f);

  const int r0 = wrow + l16;
  const int r1 = r0 + 16;
  const bool v0 = r0 < M;
  const bool v1 = r1 < M;
  const float* a0 = A + (size_t)r0 * D_SRC + quad * 8;
  const float* a1 = A + (size_t)r1 * D_SRC + quad * 8;
  const float4 z4 = make_float4(0.f, 0.f, 0.f, 0.f);

#pragma unroll
  for (int ks = 0; ks < 8; ++ks) {
    float4 x0 = v0 ? *(const float4*)(a0 + ks * 32) : z4;
    float4 x1 = v0 ? *(const float4*)(a0 + ks * 32 + 4) : z4;
    float4 y0 = v1 ? *(const float4*)(a1 + ks * 32) : z4;
    float4 y1 = v1 ? *(const float4*)(a1 + ks * 32 + 4) : z4;

    bf16x8 af0 = pack8(x0, x1);
    bf16x8 af1 = pack8(y0, y1);

#pragma unroll
    for (int j = 0; j < 8; ++j) {
      bf16x8 bfr = *(const bf16x8*)(Bs + (((size_t)ks * 8 + j) * 64 + lane) * 8);
      acc[0][j] = __builtin_amdgcn_mfma_f32_16x16x32_bf16(af0, bfr, acc[0][j], 0, 0, 0);
      acc[1][j] = __builtin_amdgcn_mfma_f32_16x16x32_bf16(af1, bfr, acc[1][j], 0, 0, 0);
    }
  }

#pragma unroll
  for (int i = 0; i < 2; ++i) {
#pragma unroll
    for (int r = 0; r < 4; ++r) {
      int grow = wrow + i * 16 + quad * 4 + r;
      if (grow < M) {
#pragma unroll
        for (int j = 0; j < 8; ++j) {
          int gcol = j * 16 + l16;
          float val = acc[i][j][r];
          C[(size_t)grow * D_REL + gcol] = val;
          if (write_bf) Cbf[(size_t)grow * D_REL + gcol] = f2bf(val);
        }
      }
    }
  }
}

// ---------------- Degree count ----------------
__global__ __launch_bounds__(256) void deg_count(
    const int* __restrict__ edge_row, int E, int* __restrict__ cnt) {
  int i = blockIdx.x * blockDim.x + threadIdx.x;
  if (i < E) atomicAdd(&cnt[edge_row[i]], 1);
}

__global__ __launch_bounds__(256) void deg_finalize(
    const int* __restrict__ cnt, int n,
    float* __restrict__ deg_out, float* __restrict__ inv_deg) {
  int i = blockIdx.x * blockDim.x + threadIdx.x;
  if (i < n) {
    int c = cnt[i];
    float d = (float)(c > 1 ? c : 1);
    deg_out[i] = d;
    inv_deg[i] = 1.0f / d;
  }
}

// ---------------- Exclusive scan of cnt -> row_ptr ----------------
#define SCAN_B 256

__global__ __launch_bounds__(SCAN_B) void scan1(
    const int* __restrict__ cnt, int n,
    int* __restrict__ row_ptr, int* __restrict__ block_sums) {
  __shared__ int s[SCAN_B];
  int i = blockIdx.x * SCAN_B + threadIdx.x;
  int v = (i < n) ? cnt[i] : 0;
  s[threadIdx.x] = v;
  __syncthreads();
#pragma unroll
  for (int off = 1; off < SCAN_B; off <<= 1) {
    int add = (threadIdx.x >= off) ? s[threadIdx.x - off] : 0;
    __syncthreads();
    s[threadIdx.x] += add;
    __syncthreads();
  }
  if (i < n) row_ptr[i] = s[threadIdx.x] - v;
  if (threadIdx.x == SCAN_B - 1) block_sums[blockIdx.x] = s[SCAN_B - 1];
}

__global__ __launch_bounds__(512) void scan2(
    int* __restrict__ block_sums, int nblocks) {
  __shared__ int s[512];
  int v = (threadIdx.x < nblocks) ? block_sums[threadIdx.x] : 0;
  s[threadIdx.x] = v;
  __syncthreads();
#pragma unroll
  for (int off = 1; off < 512; off <<= 1) {
    int add = (threadIdx.x >= off) ? s[threadIdx.x - off] : 0;
    __syncthreads();
    s[threadIdx.x] += add;
    __syncthreads();
  }
  if (threadIdx.x < nblocks) block_sums[threadIdx.x] = s[threadIdx.x] - v;
}

__global__ __launch_bounds__(SCAN_B) void scan3(
    int* __restrict__ row_ptr, const int* __restrict__ block_sums,
    int* __restrict__ cursor, int n, int E) {
  int i = blockIdx.x * SCAN_B + threadIdx.x;
  if (i < n) {
    int v = row_ptr[i] + block_sums[blockIdx.x];
    row_ptr[i] = v;
    cursor[i] = v;
  }
  if (i == 0) row_ptr[n] = E;
}

// ---------------- Scatter edges into CSR order ----------------
__global__ __launch_bounds__(256) void scatter_edges(
    const int* __restrict__ edge_row, const int* __restrict__ edge_col,
    int* __restrict__ cursor, int* __restrict__ sorted_col, int E) {
  int e = blockIdx.x * blockDim.x + threadIdx.x;
  if (e < E) {
    int r = edge_row[e];
    int pos = atomicAdd(&cursor[r], 1);
    sorted_col[pos] = edge_col[e];
  }
}

// ---------------- CSR aggregate (bf16 gather): one wave per dst row ----------------
__global__ __launch_bounds__(256) void aggregate_csr_bf16(
    const int* __restrict__ row_ptr, const int* __restrict__ sorted_col,
    const unsigned short* __restrict__ srcb, const float* __restrict__ inv_deg,
    float* __restrict__ dst, int n) {
  int wave = (blockIdx.x * blockDim.x + threadIdx.x) >> 6;
  int lane = threadIdx.x & 63;
  if (wave >= n) return;
  int beg = row_ptr[wave];
  int end = row_ptr[wave + 1];
  const unsigned short* base = srcb + lane * 2;
  float ax = 0.f, ay = 0.f, bx = 0.f, by = 0.f;
  int e = beg;
  for (; e + 1 < end; e += 2) {
    unsigned u0 = *(const unsigned*)(base + (size_t)sorted_col[e] * D_REL);
    unsigned u1 = *(const unsigned*)(base + (size_t)sorted_col[e + 1] * D_REL);
    ax += __uint_as_float(u0 << 16);
    ay += __uint_as_float(u0 & 0xffff0000u);
    bx += __uint_as_float(u1 << 16);
    by += __uint_as_float(u1 & 0xffff0000u);
  }
  if (e < end) {
    unsigned u0 = *(const unsigned*)(base + (size_t)sorted_col[e] * D_REL);
    ax += __uint_as_float(u0 << 16);
    ay += __uint_as_float(u0 & 0xffff0000u);
  }
  float wgt = inv_deg[wave];
  float2 o;
  o.x = (ax + bx) * wgt;
  o.y = (ay + by) * wgt;
  *(float2*)(dst + (size_t)wave * D_REL + lane * 2) = o;
}

// ---------------- CSR aggregate (fp32 gather fallback) ----------------
__global__ __launch_bounds__(256) void aggregate_csr(
    const int* __restrict__ row_ptr, const int* __restrict__ sorted_col,
    const float* __restrict__ src_proj, const float* __restrict__ inv_deg,
    float* __restrict__ dst, int n) {
  int wave = (blockIdx.x * blockDim.x + threadIdx.x) >> 6;
  int lane = threadIdx.x & 63;
  if (wave >= n) return;
  int beg = row_ptr[wave];
  int end = row_ptr[wave + 1];
  const float* base = src_proj + lane * 2;
  float ax = 0.f, ay = 0.f, bx = 0.f, by = 0.f;
  int e = beg;
  for (; e + 1 < end; e += 2) {
    int c0 = sorted_col[e];
    int c1 = sorted_col[e + 1];
    float2 v0 = *(const float2*)(base + (size_t)c0 * D_REL);
    float2 v1 = *(const float2*)(base + (size_t)c1 * D_REL);
    ax += v0.x; ay += v0.y;
    bx += v1.x; by += v1.y;
  }
  if (e < end) {
    int c0 = sorted_col[e];
    float2 v0 = *(const float2*)(base + (size_t)c0 * D_REL);
    ax += v0.x; ay += v0.y;
  }
  float w = inv_deg[wave];
  float2 o;
  o.x = (ax + bx) * w;
  o.y = (ay + by) * w;
  *(float2*)(dst + (size_t)wave * D_REL + lane * 2) = o;
}

extern "C" void kernel_launch(void* const* d_in, const int* in_sizes, int n_in,
                              void* d_out, int out_size, void* d_ws, size_t ws_size,
                              hipStream_t stream) {
  const float* x_src = (const float*)d_in[0];
  // d_in[1] = x_dst, d_in[3] = W_dst: dead (dst_proj is deleted in reference)
  const float* W_src = (const float*)d_in[2];
  const int* edge_row = (const int*)d_in[4];
  const int* edge_col = (const int*)d_in[5];

  const int M = in_sizes[0] / D_SRC;   // N_SRC = 100000
  const int N = in_sizes[1] / 64;      // N_DST = 100000
  const int E = in_sizes[4];           // 640000

  float* out = (float*)d_out;
  float* out_dst = out;                                  // [N, 128]
  float* out_src_proj = out + (size_t)N * D_REL;         // [M, 128]
  float* out_deg = out_src_proj + (size_t)M * D_REL;     // [N]

  // Workspace layout (256B-aligned slabs)
  char* ws = (char*)d_ws;
  size_t off = 0;
  auto alloc = [&](size_t bytes) {
    char* p = ws + off;
    off = (off + bytes + 255) & ~(size_t)255;
    return p;
  };
  int* cnt        = (int*)alloc((size_t)N * sizeof(int));
  int* row_ptr    = (int*)alloc((size_t)(N + 1) * sizeof(int));
  int* cursor     = (int*)alloc((size_t)N * sizeof(int));
  int* sorted_col = (int*)alloc((size_t)E * sizeof(int));
  float* inv_deg  = (float*)alloc((size_t)N * sizeof(float));
  int* block_sums = (int*)alloc(512 * sizeof(int));
  unsigned short* WT = (unsigned short*)alloc((size_t)D_REL * D_SRC * sizeof(unsigned short));
  unsigned short* src_bf = (unsigned short*)alloc((size_t)M * D_REL * sizeof(unsigned short));
  const bool use_bf = (ws_size >= off);
  unsigned short* Abf = (unsigned short*)alloc((size_t)M * D_SRC * sizeof(unsigned short));
  const bool use_abf = (ws_size >= off);

  const int scan_blocks = (N + SCAN_B - 1) / SCAN_B;  // 391 <= 512

  hipMemsetAsync(cnt, 0, (size_t)N * sizeof(int), stream);

  // W bf16, MFMA B-fragment order
  convert_wt<<<16, 256, 0, stream>>>(W_src, WT);

  // A fp32 -> bf16 (streaming) if workspace allows
  if (use_abf) {
    long total8 = ((long)M * D_SRC) / 8;
    int cblocks = (int)((total8 + 255) / 256);
    convert_a<<<cblocks, 256, 0, stream>>>(x_src, Abf, total8);
  }

  // Degree + inv_deg
  deg_count<<<(E + 255) / 256, 256, 0, stream>>>(edge_row, E, cnt);
  deg_finalize<<<(N + 255) / 256, 256, 0, stream>>>(cnt, N, out_deg, inv_deg);

  // Exclusive scan cnt -> row_ptr; cursor = row_ptr
  scan1<<<scan_blocks, SCAN_B, 0, stream>>>(cnt, N, row_ptr, block_sums);
  scan2<<<1, 512, 0, stream>>>(block_sums, scan_blocks);
  scan3<<<scan_blocks, SCAN_B, 0, stream>>>(row_ptr, block_sums, cursor, N, E);

  // CSR scatter
  scatter_edges<<<(E + 255) / 256, 256, 0, stream>>>(edge_row, edge_col, cursor,
                                                     sorted_col, E);

  // MFMA GEMM: src_proj fp32 (+ bf16 copy for the gather if ws allows)
  if (use_abf) {
    gemm_mfma_bf<<<(M + GBM - 1) / GBM, 256, 0, stream>>>(
        Abf, WT, out_src_proj, src_bf, M, use_bf ? 1 : 0);
  } else {
    gemm_mfma<<<(M + GBM - 1) / GBM, 256, 0, stream>>>(
        x_src, WT, out_src_proj, src_bf, M, use_bf ? 1 : 0);
  }

  // Gather-aggregate: 1 wave per dst row, 4 waves per block
  if (use_bf) {
    aggregate_csr_bf16<<<(N + 3) / 4, 256, 0, stream>>>(row_ptr, sorted_col, src_bf,
                                                        inv_deg, out_dst, N);
  } else {
    aggregate_csr<<<(N + 3) / 4, 256, 0, stream>>>(row_ptr, sorted_col, out_src_proj,
                                                   inv_deg, out_dst, N);
  }
}

// Round 5
// 329.979 us; speedup vs baseline: 1.2063x; 1.0242x over previous
//
#include <hip/hip_runtime.h>
#include <hip/hip_bf16.h>

// Problem constants (RelKDAdapter_60284160966709)
#define D_SRC 256
#define D_REL 128

typedef short bf16x8 __attribute__((ext_vector_type(8)));
typedef float f32x4 __attribute__((ext_vector_type(4)));

__device__ __forceinline__ unsigned short f2bf(float f) {
  unsigned u = __float_as_uint(f);
  unsigned r = 0x7FFFu + ((u >> 16) & 1u);
  return (unsigned short)((u + r) >> 16);
}

// 2x fp32 -> packed bf16 pair via v_cvt_pk_bf16_f32 (compiler-generated, RNE)
__device__ __forceinline__ unsigned cvt2(float lo, float hi) {
  __hip_bfloat162 h = __float22bfloat162_rn(make_float2(lo, hi));
  return *reinterpret_cast<unsigned*>(&h);
}

__device__ __forceinline__ bf16x8 pack8(float4 a, float4 b) {
  union { unsigned u[4]; bf16x8 v; } r;
  r.u[0] = cvt2(a.x, a.y);
  r.u[1] = cvt2(a.z, a.w);
  r.u[2] = cvt2(b.x, b.y);
  r.u[3] = cvt2(b.z, b.w);
  return r.v;
}

// ---------------- W -> bf16 in MFMA B-fragment order ----------------
// Wfrag layout: [ks (8)][j (8)][lane (64)][8 bf16], 16B per (ks,j,lane) slot.
// Frag semantics (mfma_f32_16x16x32_bf16 B operand): col n = j*16 + (lane&15),
// k = ks*32 + (lane>>4)*8 + m.  Value = bf16(W[k][n]) (W stored [K=256][N=128]).
// Layout harness-verified rounds 1-4 (passed, absmax 0.03125).
__global__ __launch_bounds__(256) void convert_wt(
    const float* __restrict__ W, unsigned short* __restrict__ Wfrag) {
  int idx = blockIdx.x * 256 + threadIdx.x;  // 0..4095 (8*8*64)
  int lane = idx & 63;
  int j = (idx >> 6) & 7;
  int ks = idx >> 9;
  int n = j * 16 + (lane & 15);
  int k = ks * 32 + (lane >> 4) * 8;
  bf16x8 o;
#pragma unroll
  for (int m = 0; m < 8; ++m)
    o[m] = (short)f2bf(W[(size_t)(k + m) * D_REL + n]);
  *(bf16x8*)(Wfrag + (size_t)idx * 8) = o;  // 16B store, frag-linear
}

#define GBM 128

// ---------------- MFMA GEMM v5: fp32 A direct, register-prefetch (fused cvt) ----------------
// r4 lesson applied to fp32 A: issue ALL 16 A float4 loads up front (explicit
// register block, 64 VGPR in flight), stage B to LDS concurrently, one barrier
// (its vmcnt(0) drain completes everything), then cvt+pure-MFMA stream.
// 8 waves x 16 rows = 128 rows/block; per wave 16 rows x 128 cols, acc 8xf32x4.
__global__ __launch_bounds__(512) void gemm_mfma(
    const float* __restrict__ A,               // [M, 256] fp32
    const unsigned short* __restrict__ Wfrag,  // [8][8][64][8] bf16 frag-order
    float* __restrict__ C,                     // [M, 128] fp32 out
    unsigned short* __restrict__ Cbf,          // [M, 128] bf16 copy
    int M, int write_bf) {
  __shared__ unsigned short Bs[8 * 8 * 64 * 8];  // 64 KB, frag-linear

  const int t = threadIdx.x;
  const int w = t >> 6;        // wave 0..7
  const int lane = t & 63;
  const int quad = lane >> 4;
  const int l16 = lane & 15;
  const int wrow = blockIdx.x * GBM + w * 16;

  const int r0 = wrow + l16;
  const int r0c = (r0 < M) ? r0 : (M - 1);   // clamp: branchless, always-valid loads
  const float* a0 = A + (size_t)r0c * D_SRC + quad * 8;

  // --- Issue all 16 A float4 loads back-to-back (64 VGPR in flight) ---
  float4 afp[16];
#pragma unroll
  for (int ks = 0; ks < 8; ++ks) {
    afp[2 * ks]     = *(const float4*)(a0 + ks * 32);
    afp[2 * ks + 1] = *(const float4*)(a0 + ks * 32 + 4);
  }

  // --- Stage all of B once: 4096 x 16B slots, 8 per thread, coalesced ---
#pragma unroll
  for (int i = 0; i < 8; ++i) {
    int s = t + 512 * i;
    *(uint4*)(Bs + (size_t)s * 8) = *(const uint4*)(Wfrag + (size_t)s * 8);
  }
  __syncthreads();  // only barrier; drains A loads + B staging together

  f32x4 acc[8];
#pragma unroll
  for (int j = 0; j < 8; ++j) acc[j] = (f32x4)(0.0f);

  // --- cvt + pure LDS-read + MFMA stream ---
#pragma unroll
  for (int ks = 0; ks < 8; ++ks) {
    bf16x8 af = pack8(afp[2 * ks], afp[2 * ks + 1]);
#pragma unroll
    for (int j = 0; j < 8; ++j) {
      bf16x8 bfr = *(const bf16x8*)(Bs + (((size_t)ks * 8 + j) * 64 + lane) * 8);
      acc[j] = __builtin_amdgcn_mfma_f32_16x16x32_bf16(af, bfr, acc[j], 0, 0, 0);
    }
  }

  // Epilogue: C/D layout col=lane&15, row=quad*4+reg
#pragma unroll
  for (int r = 0; r < 4; ++r) {
    int grow = wrow + quad * 4 + r;
    if (grow < M) {
#pragma unroll
      for (int j = 0; j < 8; ++j) {
        int gcol = j * 16 + l16;
        float val = acc[j][r];
        C[(size_t)grow * D_REL + gcol] = val;
        if (write_bf) Cbf[(size_t)grow * D_REL + gcol] = f2bf(val);
      }
    }
  }
}

// ---------------- Degree count ----------------
__global__ __launch_bounds__(256) void deg_count(
    const int* __restrict__ edge_row, int E, int* __restrict__ cnt) {
  int i = blockIdx.x * blockDim.x + threadIdx.x;
  if (i < E) atomicAdd(&cnt[edge_row[i]], 1);
}

// ---------------- Exclusive scan of cnt -> row_ptr (+ fused deg/inv_deg) ----------------
#define SCAN_B 256

__global__ __launch_bounds__(SCAN_B) void scan1(
    const int* __restrict__ cnt, int n,
    int* __restrict__ row_ptr, int* __restrict__ block_sums,
    float* __restrict__ deg_out, float* __restrict__ inv_deg) {
  __shared__ int s[SCAN_B];
  int i = blockIdx.x * SCAN_B + threadIdx.x;
  int v = (i < n) ? cnt[i] : 0;
  if (i < n) {
    float d = (float)(v > 1 ? v : 1);
    deg_out[i] = d;
    inv_deg[i] = 1.0f / d;
  }
  s[threadIdx.x] = v;
  __syncthreads();
#pragma unroll
  for (int off = 1; off < SCAN_B; off <<= 1) {
    int add = (threadIdx.x >= off) ? s[threadIdx.x - off] : 0;
    __syncthreads();
    s[threadIdx.x] += add;
    __syncthreads();
  }
  if (i < n) row_ptr[i] = s[threadIdx.x] - v;
  if (threadIdx.x == SCAN_B - 1) block_sums[blockIdx.x] = s[SCAN_B - 1];
}

__global__ __launch_bounds__(512) void scan2(
    int* __restrict__ block_sums, int nblocks) {
  __shared__ int s[512];
  int v = (threadIdx.x < nblocks) ? block_sums[threadIdx.x] : 0;
  s[threadIdx.x] = v;
  __syncthreads();
#pragma unroll
  for (int off = 1; off < 512; off <<= 1) {
    int add = (threadIdx.x >= off) ? s[threadIdx.x - off] : 0;
    __syncthreads();
    s[threadIdx.x] += add;
    __syncthreads();
  }
  if (threadIdx.x < nblocks) block_sums[threadIdx.x] = s[threadIdx.x] - v;
}

__global__ __launch_bounds__(SCAN_B) void scan3(
    int* __restrict__ row_ptr, const int* __restrict__ block_sums,
    int* __restrict__ cursor, int n, int E) {
  int i = blockIdx.x * SCAN_B + threadIdx.x;
  if (i < n) {
    int v = row_ptr[i] + block_sums[blockIdx.x];
    row_ptr[i] = v;
    cursor[i] = v;
  }
  if (i == 0) row_ptr[n] = E;
}

// ---------------- Scatter edges into CSR order ----------------
__global__ __launch_bounds__(256) void scatter_edges(
    const int* __restrict__ edge_row, const int* __restrict__ edge_col,
    int* __restrict__ cursor, int* __restrict__ sorted_col, int E) {
  int e = blockIdx.x * blockDim.x + threadIdx.x;
  if (e < E) {
    int r = edge_row[e];
    int pos = atomicAdd(&cursor[r], 1);
    sorted_col[pos] = edge_col[e];
  }
}

// ---------------- CSR aggregate (bf16 gather): one wave per dst row, 2 edges/iter ----------------
// Wave split into two 32-lane halves; each half gathers a different edge's row
// at 8 B/lane (uint2 = 4 bf16) -> 512 B/instr/wave, half the trip count.
// Cross-half combine via 4x shfl_xor(32); lanes 0-31 write float4.
__global__ __launch_bounds__(256) void aggregate_csr_bf16(
    const int* __restrict__ row_ptr, const int* __restrict__ sorted_col,
    const unsigned short* __restrict__ srcb, const float* __restrict__ inv_deg,
    float* __restrict__ dst, int n) {
  int wave = (blockIdx.x * blockDim.x + threadIdx.x) >> 6;
  int lane = threadIdx.x & 63;
  if (wave >= n) return;
  int beg = row_ptr[wave];
  int end = row_ptr[wave + 1];
  const int half = lane >> 5;   // 0 or 1: which edge of the pair
  const int q = lane & 31;      // elements q*4 .. q*4+3
  const unsigned short* base = srcb + q * 4;

  float a0 = 0.f, a1 = 0.f, a2 = 0.f, a3 = 0.f;
  int e = beg;
  for (; e + 1 < end; e += 2) {
    int col = sorted_col[e + half];
    uint2 u = *(const uint2*)(base + (size_t)col * D_REL);
    a0 += __uint_as_float(u.x << 16);
    a1 += __uint_as_float(u.x & 0xffff0000u);
    a2 += __uint_as_float(u.y << 16);
    a3 += __uint_as_float(u.y & 0xffff0000u);
  }
  if (e < end && half == 0) {   // odd tail: lower half only
    int col = sorted_col[e];
    uint2 u = *(const uint2*)(base + (size_t)col * D_REL);
    a0 += __uint_as_float(u.x << 16);
    a1 += __uint_as_float(u.x & 0xffff0000u);
    a2 += __uint_as_float(u.y << 16);
    a3 += __uint_as_float(u.y & 0xffff0000u);
  }
  // combine halves (lane L += lane L^32)
  a0 += __shfl_xor(a0, 32);
  a1 += __shfl_xor(a1, 32);
  a2 += __shfl_xor(a2, 32);
  a3 += __shfl_xor(a3, 32);

  if (half == 0) {
    float wgt = inv_deg[wave];
    float4 o;
    o.x = a0 * wgt; o.y = a1 * wgt; o.z = a2 * wgt; o.w = a3 * wgt;
    *(float4*)(dst + (size_t)wave * D_REL + q * 4) = o;
  }
}

// ---------------- CSR aggregate (fp32 gather fallback) ----------------
__global__ __launch_bounds__(256) void aggregate_csr(
    const int* __restrict__ row_ptr, const int* __restrict__ sorted_col,
    const float* __restrict__ src_proj, const float* __restrict__ inv_deg,
    float* __restrict__ dst, int n) {
  int wave = (blockIdx.x * blockDim.x + threadIdx.x) >> 6;
  int lane = threadIdx.x & 63;
  if (wave >= n) return;
  int beg = row_ptr[wave];
  int end = row_ptr[wave + 1];
  const float* base = src_proj + lane * 2;
  float ax = 0.f, ay = 0.f, bx = 0.f, by = 0.f;
  int e = beg;
  for (; e + 1 < end; e += 2) {
    int c0 = sorted_col[e];
    int c1 = sorted_col[e + 1];
    float2 v0 = *(const float2*)(base + (size_t)c0 * D_REL);
    float2 v1 = *(const float2*)(base + (size_t)c1 * D_REL);
    ax += v0.x; ay += v0.y;
    bx += v1.x; by += v1.y;
  }
  if (e < end) {
    int c0 = sorted_col[e];
    float2 v0 = *(const float2*)(base + (size_t)c0 * D_REL);
    ax += v0.x; ay += v0.y;
  }
  float w = inv_deg[wave];
  float2 o;
  o.x = (ax + bx) * w;
  o.y = (ay + by) * w;
  *(float2*)(dst + (size_t)wave * D_REL + lane * 2) = o;
}

extern "C" void kernel_launch(void* const* d_in, const int* in_sizes, int n_in,
                              void* d_out, int out_size, void* d_ws, size_t ws_size,
                              hipStream_t stream) {
  const float* x_src = (const float*)d_in[0];
  // d_in[1] = x_dst, d_in[3] = W_dst: dead (dst_proj is deleted in reference)
  const float* W_src = (const float*)d_in[2];
  const int* edge_row = (const int*)d_in[4];
  const int* edge_col = (const int*)d_in[5];

  const int M = in_sizes[0] / D_SRC;   // N_SRC = 100000
  const int N = in_sizes[1] / 64;      // N_DST = 100000
  const int E = in_sizes[4];           // 640000

  float* out = (float*)d_out;
  float* out_dst = out;                                  // [N, 128]
  float* out_src_proj = out + (size_t)N * D_REL;         // [M, 128]
  float* out_deg = out_src_proj + (size_t)M * D_REL;     // [N]

  // Workspace layout (256B-aligned slabs)
  char* ws = (char*)d_ws;
  size_t off = 0;
  auto alloc = [&](size_t bytes) {
    char* p = ws + off;
    off = (off + bytes + 255) & ~(size_t)255;
    return p;
  };
  int* cnt        = (int*)alloc((size_t)N * sizeof(int));
  int* row_ptr    = (int*)alloc((size_t)(N + 1) * sizeof(int));
  int* cursor     = (int*)alloc((size_t)N * sizeof(int));
  int* sorted_col = (int*)alloc((size_t)E * sizeof(int));
  float* inv_deg  = (float*)alloc((size_t)N * sizeof(float));
  int* block_sums = (int*)alloc(512 * sizeof(int));
  unsigned short* WT = (unsigned short*)alloc((size_t)D_REL * D_SRC * sizeof(unsigned short));
  unsigned short* src_bf = (unsigned short*)alloc((size_t)M * D_REL * sizeof(unsigned short));
  const bool use_bf = (ws_size >= off);

  const int scan_blocks = (N + SCAN_B - 1) / SCAN_B;  // 391 <= 512

  hipMemsetAsync(cnt, 0, (size_t)N * sizeof(int), stream);

  // W bf16, MFMA B-fragment order
  convert_wt<<<16, 256, 0, stream>>>(W_src, WT);

  // Degree
  deg_count<<<(E + 255) / 256, 256, 0, stream>>>(edge_row, E, cnt);

  // Exclusive scan cnt -> row_ptr (+ deg/inv_deg fused); cursor = row_ptr
  scan1<<<scan_blocks, SCAN_B, 0, stream>>>(cnt, N, row_ptr, block_sums,
                                            out_deg, inv_deg);
  scan2<<<1, 512, 0, stream>>>(block_sums, scan_blocks);
  scan3<<<scan_blocks, SCAN_B, 0, stream>>>(row_ptr, block_sums, cursor, N, E);

  // CSR scatter
  scatter_edges<<<(E + 255) / 256, 256, 0, stream>>>(edge_row, edge_col, cursor,
                                                     sorted_col, E);

  // MFMA GEMM (fused fp32->bf16 cvt): src_proj fp32 + bf16 copy for the gather
  gemm_mfma<<<(M + GBM - 1) / GBM, 512, 0, stream>>>(
      x_src, WT, out_src_proj, src_bf, M, use_bf ? 1 : 0);

  // Gather-aggregate: 1 wave per dst row, 4 waves per block
  if (use_bf) {
    aggregate_csr_bf16<<<(N + 3) / 4, 256, 0, stream>>>(row_ptr, sorted_col, src_bf,
                                                        inv_deg, out_dst, N);
  } else {
    aggregate_csr<<<(N + 3) / 4, 256, 0, stream>>>(row_ptr, sorted_col, out_src_proj,
                                                   inv_deg, out_dst, N);
  }
}